// Round 12
// baseline (214.720 us; speedup 1.0000x reference)
//
#include <hip/hip_runtime.h>

typedef __attribute__((ext_vector_type(8))) short bf16x8;
typedef __attribute__((ext_vector_type(4))) float f32x4;

#define MFMA16(a,b,c) __builtin_amdgcn_mfma_f32_16x16x32_bf16((a),(b),(c),0,0,0)

__device__ __forceinline__ float b2f(unsigned short u){
  union { unsigned u; float f; } x; x.u = ((unsigned)u) << 16; return x.f;
}
__device__ __forceinline__ unsigned short f2b(float f){
  union { float f; unsigned u; } x; x.f = f;
  unsigned r = x.u + 0x7FFFu + ((x.u >> 16) & 1u);
  return (unsigned short)(r >> 16);
}
__device__ __forceinline__ unsigned pk_rne(float a, float b){
  unsigned ua = __float_as_uint(a), ub = __float_as_uint(b);
  ua += 0x7FFFu + ((ua >> 16) & 1u);
  ub += 0x7FFFu + ((ub >> 16) & 1u);
  return __builtin_amdgcn_perm(ub, ua, 0x07060302u);
}
__device__ __forceinline__ unsigned pk_trunc(float a, float b){
  return __builtin_amdgcn_perm(__float_as_uint(b), __float_as_uint(a), 0x07060302u);
}
__device__ __forceinline__ bf16x8 mk8(unsigned a, unsigned b, unsigned c, unsigned d){
  union { uint4 u; bf16x8 h; } x; x.u = make_uint4(a,b,c,d); return x.h;
}
// cluster-index bit rotation so register Sᵀ fragments align with PV's B-operand k-slots
__device__ __forceinline__ int permp(int cl){
  return (cl & 0xE0) | (((cl >> 2) & 3) << 3) | (((cl >> 4) & 1) << 2) | (cl & 3);
}

typedef __attribute__((address_space(3))) unsigned int lds_u32;
typedef const __attribute__((address_space(1))) unsigned int glb_u32;
__device__ __forceinline__ void gl_lds16(const void* g, void* l){
  __builtin_amdgcn_global_load_lds((glb_u32*)g, (lds_u32*)l, 16, 0, 0);
}

// ---------------- merged prep + cluster means ----------------
__global__ __launch_bounds__(192) void prep_means_kernel(
    const float* __restrict__ pos, unsigned* __restrict__ pmax,
    const float* __restrict__ qkv_w, unsigned short* __restrict__ qkvwb,
    const float* __restrict__ proj_w, unsigned short* __restrict__ projwb,
    const float* __restrict__ feat,
    const int* __restrict__ member_idx, const int* __restrict__ batch_idx,
    unsigned short* __restrict__ fm, float* __restrict__ pm,
    unsigned short* __restrict__ featb)
{
  int bid = blockIdx.x, t = threadIdx.x;
  if (bid < 1024){
    int g = t / 96, tl = t - g*96;
    int z = bid;
    __shared__ int bases[32];
    __shared__ float4 part[96];
    if (t < 32) bases[t] = batch_idx[z*32 + t]*8192 + member_idx[z*32 + t];
    __syncthreads();
    // pos mean: one wave-load + tree reduce on lanes 0..31
    if (t < 32){
      float2 pp = ((const float2*)pos)[bases[t]];
      #pragma unroll
      for (int off = 16; off >= 1; off >>= 1){
        pp.x += __shfl_xor(pp.x, off, 32);
        pp.y += __shfl_xor(pp.y, off, 32);
      }
      if (t == 0){ pm[z*2] = pp.x*(1.f/32.f); pm[z*2+1] = pp.y*(1.f/32.f); }
    }
    // feat: 16 gather loads in flight, then stores + accumulate
    float4 v[16]; int rows[16];
    const float4* f4 = (const float4*)feat;
    #pragma unroll
    for (int m = 0; m < 16; m++){
      rows[m] = bases[g*16 + m];
      v[m] = f4[(long)rows[m]*96 + tl];
    }
    float4 a = {0.f,0.f,0.f,0.f};
    #pragma unroll
    for (int m = 0; m < 16; m++){
      *(uint2*)(featb + (long)rows[m]*384 + tl*4) =
          make_uint2(pk_rne(v[m].x, v[m].y), pk_rne(v[m].z, v[m].w));
      a.x += v[m].x; a.y += v[m].y; a.z += v[m].z; a.w += v[m].w;
    }
    if (g == 1) part[tl] = a;
    __syncthreads();
    if (g == 0){
      float4 b = part[tl];
      a.x += b.x; a.y += b.y; a.z += b.z; a.w += b.w;
      unsigned d0 = pk_rne(a.x*(1.f/32.f), a.y*(1.f/32.f));
      unsigned d1 = pk_rne(a.z*(1.f/32.f), a.w*(1.f/32.f));
      *(uint2*)(fm + (long)z*384 + tl*4) = make_uint2(d0, d1);
    }
  } else if (bid < 1408){
    int u = (bid - 1024)*192 + t;     // [0, 73728)
    const float* in; unsigned short* o; long i;
    if (u < 55296){ in = qkv_w;  o = qkvwb;  i = u; }
    else          { in = proj_w; o = projwb; i = u - 55296; }
    const float4* p = (const float4*)(in + i*8);
    float4 a = p[0], b = p[1];
    *(uint4*)(o + i*8) = make_uint4(pk_rne(a.x,a.y), pk_rne(a.z,a.w),
                                    pk_rne(b.x,b.y), pk_rne(b.z,b.w));
  } else {
    int i = (bid - 1408)*192 + t;
    if (i < 16384){
      float4 v = ((const float4*)pos)[i];
      float m0 = fmaxf(v.x, v.z), m1 = fmaxf(v.y, v.w);
      #pragma unroll
      for (int off = 32; off >= 1; off >>= 1){
        m0 = fmaxf(m0, __shfl_xor(m0, off, 64));
        m1 = fmaxf(m1, __shfl_xor(m1, off, 64));
      }
      if ((t & 63) == 0){
        atomicMax(&pmax[0], __float_as_uint(m0));
        atomicMax(&pmax[1], __float_as_uint(m1));
      }
    }
  }
}

// ---------------- merged kv-GEMM + wt + q-GEMM, 512 blocks ----------------
// kh written LINEAR (r7 form) — attnproj now reads K directly from L2, no LDS.
__global__ __launch_bounds__(512) void kvq_kernel(
    const unsigned short* __restrict__ fm,     // (1024,384) bf16 cluster means
    const unsigned short* __restrict__ featb,  // (32768,384) bf16
    const unsigned short* __restrict__ qkvwb,  // (1152,384) bf16; rows 0..383 = Wq
    const float* __restrict__ qkv_b,           // (1152)
    const float* __restrict__ pm, const float* __restrict__ pmaxf,
    const float* __restrict__ pos_w, const float* __restrict__ pos_b,
    unsigned short* __restrict__ kh, unsigned short* __restrict__ vt,
    unsigned short* __restrict__ wt,
    unsigned short* __restrict__ q_s, float q_scale)
{
  __shared__ unsigned short As[64*64];    // 8 KB
  __shared__ unsigned short Ws[384*64];   // 48 KB
  __shared__ unsigned short wtS[256];
  const int K = 384;
  int tid = threadIdx.x;
  int lane = tid & 63, wave = tid >> 6;
  int l15 = lane & 15, quad = lane >> 4;
  int sw = l15 & 7;
  int srow = tid >> 3, sc8 = tid & 7;     // 512 thr: srow 0..63

  int qtile;
  if (blockIdx.x < 96){
    // ================= kv GEMM =================
    int mt = blockIdx.x / 6, nt = blockIdx.x - mt*6;
    int m0 = mt << 6, n0 = nt << 7;
    int b = m0 >> 8, cl0 = m0 & 255;
    const unsigned short* W = qkvwb + 384*384;
    // wt prologue: this block's 4 heads x 64 clusters (bit-identical to old bias_kernel)
    if (nt >= 3 && tid < 256){
      int lh = tid >> 6, lc = tid & 63;
      int h = ((n0 - 384) >> 5) + lh;
      int cl = cl0 + lc;
      float p0 = pm[(b*256 + cl)*2]   / pmaxf[0];
      float p1 = pm[(b*256 + cl)*2+1] / pmaxf[1];
      float bias = p0*pos_w[h*2] + p1*pos_w[h*2+1] + pos_b[h];
      unsigned short wv = f2b(exp2f(bias * 1.44269504088896340f));
      wtS[lh*64 + lc] = wv;
      wt[(((long)(b*12 + h)) << 8) + permp(cl)] = wv;
    }
    int wr = (wave >> 2) << 5, wc = (wave & 3) << 5;
    f32x4 acc[2][2];
    #pragma unroll
    for (int i = 0; i < 2; i++)
      #pragma unroll
      for (int j = 0; j < 2; j++) acc[i][j] = (f32x4){0.f,0.f,0.f,0.f};

    for (int k0 = 0; k0 < K; k0 += 64){
      __syncthreads();
      int gc8 = sc8 ^ (srow & 7);
      gl_lds16(fm + (long)(m0+srow)*K + k0 + gc8*8, As + wave*512);
      #pragma unroll
      for (int it = 0; it < 2; it++){
        int r = it*64 + srow;
        int g2 = sc8 ^ (r & 7);
        gl_lds16(W + (long)(n0+r)*K + k0 + g2*8, Ws + it*4096 + wave*512);
      }
      __syncthreads();
      #pragma unroll
      for (int kk = 0; kk < 2; kk++){
        bf16x8 af[2], bfr[2];
        #pragma unroll
        for (int i = 0; i < 2; i++)
          af[i] = *(const bf16x8*)(As + (wr + i*16 + l15)*64 + (((kk<<2)+quad) ^ sw)*8);
        #pragma unroll
        for (int j = 0; j < 2; j++)
          bfr[j] = *(const bf16x8*)(Ws + (wc + j*16 + l15)*64 + (((kk<<2)+quad) ^ sw)*8);
        #pragma unroll
        for (int i = 0; i < 2; i++)
          #pragma unroll
          for (int j = 0; j < 2; j++)
            acc[i][j] = MFMA16(af[i], bfr[j], acc[i][j]);
      }
    }

    #pragma unroll
    for (int j = 0; j < 2; j++){
      int col = n0 + wc + j*16 + l15;
      float bv = qkv_b[384 + col];
      #pragma unroll
      for (int i = 0; i < 2; i++){
        #pragma unroll
        for (int r = 0; r < 4; r++){
          float v = acc[i][j][r] + bv;
          int lr = wr + i*16 + quad*4 + r;     // local row 0..63
          int cl = cl0 + lr;
          if (col < 384){
            int h = col >> 5, ch = col & 31;
            kh[((((long)b*12 + h)*256 + cl)*32) + ch] = f2b(v);
          } else {
            int cn = col - 384;
            int h = cn >> 5, ch = cn & 31;
            int pp = permp(cl);
            int c8 = (pp >> 3) ^ (ch & 7);
            float w = b2f(wtS[(wave & 3)*64 + lr]);
            vt[(((long)b*12 + h)*32 + ch)*256 + c8*8 + (pp & 7)] = f2b(v * w);
          }
        }
      }
    }
    qtile = 416 + blockIdx.x;
  } else {
    qtile = blockIdx.x - 96;
  }

  // ================= q GEMM (single-buffer, 2 blocks/CU structure) =================
  {
    int m0 = qtile << 6;
    f32x4 acc[4][3];
    #pragma unroll
    for (int i = 0; i < 4; i++)
      #pragma unroll
      for (int j = 0; j < 3; j++) acc[i][j] = (f32x4){0.f,0.f,0.f,0.f};

    for (int k0 = 0; k0 < K; k0 += 64){
      __syncthreads();
      int gc8 = sc8 ^ (srow & 7);
      gl_lds16(featb + (long)(m0+srow)*K + k0 + gc8*8, As + wave*512);
      #pragma unroll
      for (int it = 0; it < 6; it++){
        int r = it*64 + srow;
        int g2 = sc8 ^ (r & 7);
        gl_lds16(qkvwb + (long)r*K + k0 + g2*8, Ws + it*4096 + wave*512);
      }
      __syncthreads();
      #pragma unroll
      for (int kk = 0; kk < 2; kk++){
        bf16x8 af[4];
        #pragma unroll
        for (int i = 0; i < 4; i++)
          af[i] = *(const bf16x8*)(As + (i*16 + l15)*64 + (((kk<<2)+quad) ^ sw)*8);
        #pragma unroll
        for (int j = 0; j < 3; j++){
          bf16x8 bfr = *(const bf16x8*)(Ws + (wave*48 + j*16 + l15)*64 + (((kk<<2)+quad) ^ sw)*8);
          #pragma unroll
          for (int i = 0; i < 4; i++)
            acc[i][j] = MFMA16(af[i], bfr, acc[i][j]);
        }
      }
    }

    #pragma unroll
    for (int j = 0; j < 3; j++){
      int col = wave*48 + j*16 + l15;
      float bv = qkv_b[col];
      #pragma unroll
      for (int i = 0; i < 4; i++){
        int row0 = m0 + i*16 + quad*4;
        #pragma unroll
        for (int r = 0; r < 4; r++){
          float v = (acc[i][j][r] + bv) * q_scale;
          int row = row0 + r;
          int bb = row >> 13, tok = row & 8191;
          q_s[((((long)(bb*12 + (col >> 5))) << 13) + tok)*32 + (col & 31)] = f2b(v);
        }
      }
    }
  }
}

// ---------------- FUSED attention + proj: DIRECT-L2 K/V reads, no staging ----------------
// kh+vt+wt = 1.5 MB, L2-resident (each (b,h) slice re-read by 128 blocks).
// LDS-staging it was pure overhead (guide CM#7): r7-r11's 6x serial
// {stage 65KB -> vmcnt(0) drain -> barrier} idled all waves per iteration while
// no pipe exceeded 45%. Now: every K/V/w fragment is a per-lane 16B contiguous
// global load (33 independent loads in flight per wave-iter), LDS holds only a
// double-buffered oS (16 KB), and each iteration has ONE barrier (pure LDS sync,
// no vmcnt drain). W_{i+2}-vs-R_i hazard on oS buffers is covered by the barrier
// chain (W_{i+2} is after B_{i+1}, which is after R_i).
__global__ __launch_bounds__(512, 4) void attnproj_kernel(
    const unsigned short* __restrict__ qhm,    // (B*H,8192,32) bf16, scale*log2e folded
    const unsigned short* __restrict__ kh,     // (B,H,256,32) bf16, linear
    const unsigned short* __restrict__ vt,     // (B,H,32,256) bf16, permp-packed, w-folded
    const unsigned short* __restrict__ wt,     // (B*H,256) bf16, permp'd
    const unsigned short* __restrict__ projwb, // (384,384) bf16
    const float* __restrict__ proj_b,
    float* __restrict__ out)                   // (B*8192,384) f32
{
  __shared__ unsigned short oS[2][64*64];      // 16 KB: [buf][tok][ch oct^sw]

  int bid = blockIdx.x;
  int b = bid >> 7;
  int t0 = (bid & 127) << 6;
  int tid = threadIdx.x, lane = tid & 63, wave = tid >> 6;
  int l15 = lane & 15, quad = lane >> 4;
  int sw = l15 & 7;
  int hsel = wave >> 2, ti = wave & 3;

  f32x4 acc[4][3];
  #pragma unroll
  for (int i = 0; i < 4; i++)
    #pragma unroll
    for (int j = 0; j < 3; j++) acc[i][j] = (f32x4){0.f,0.f,0.f,0.f};

  for (int it = 0; it < 6; it++){
    int head = 2*it + hsel;
    long bh = (long)b*12 + head;
    const unsigned short* kb = kh + bh*8192;   // [256][32]
    const unsigned short* vb = vt + bh*8192;   // [32][256] packed
    const unsigned short* wb = wt + bh*256;

    bf16x8 aq = *(const bf16x8*)(qhm + (bh*8192 + t0 + ti*16 + l15)*32 + quad*8);

    f32x4 o0 = {0.f,0.f,0.f,0.f}, o1 = {0.f,0.f,0.f,0.f}, os = {0.f,0.f,0.f,0.f};
    #pragma unroll
    for (int ks8 = 0; ks8 < 8; ks8++){
      // K fragments direct from L2: 16B/lane contiguous
      bf16x8 bk0 = *(const bf16x8*)(kb + (32*ks8 + l15)*32 + quad*8);
      bf16x8 bk1 = *(const bf16x8*)(kb + (32*ks8 + 16 + l15)*32 + quad*8);
      const f32x4 z4 = {0.f,0.f,0.f,0.f};
      f32x4 s0 = MFMA16(bk0, aq, z4);
      f32x4 s1 = MFMA16(bk1, aq, z4);
      #pragma unroll
      for (int c = 0; c < 4; c++){ s0[c] = exp2f(s0[c]); s1[c] = exp2f(s1[c]); }
      bf16x8 pf = mk8(pk_trunc(s0[0],s0[1]), pk_trunc(s0[2],s0[3]),
                      pk_trunc(s1[0],s1[1]), pk_trunc(s1[2],s1[3]));
      // V/w fragments direct from L2 (same data the LDS copy held before)
      int c8 = (4*ks8 + quad) ^ sw;
      bf16x8 a0 = *(const bf16x8*)(vb + l15*256      + c8*8);
      bf16x8 a1 = *(const bf16x8*)(vb + (16+l15)*256 + c8*8);
      bf16x8 wf = *(const bf16x8*)(wb + ks8*32 + quad*8);
      o0 = MFMA16(a0, pf, o0);
      o1 = MFMA16(a1, pf, o1);
      os = MFMA16(wf, pf, os);
    }

    // normalize + store O tile [64 tok][64 ch] bf16 with oct^sw swizzle into buf it&1
    // (bf16-rounded at the same point as the old global ao write -> bit-identical)
    float inv = 1.f / os[0];
    unsigned short* ob = &oS[it & 1][0];
    int tokLoc = ti*16 + l15;                 // tokLoc&7 == sw
    int oct0 = hsel*4 + (quad >> 1);          // o0: ch hsel*32+quad*4..+3 ; o1: +16
    int wi = (quad & 1)*4;
    *(uint2*)(ob + tokLoc*64 + ((oct0 ^ sw)*8 + wi)) =
        make_uint2(pk_rne(o0[0]*inv, o0[1]*inv), pk_rne(o0[2]*inv, o0[3]*inv));
    *(uint2*)(ob + tokLoc*64 + (((oct0+2) ^ sw)*8 + wi)) =
        make_uint2(pk_rne(o1[0]*inv, o1[1]*inv), pk_rne(o1[2]*inv, o1[3]*inv));
    __syncthreads();                          // O visible (LDS-only sync, no vmcnt drain)

    // proj accumulate: BK=64 (this head-pair's channels); B direct from L2
    #pragma unroll
    for (int kk = 0; kk < 2; kk++){
      bf16x8 af[4];
      #pragma unroll
      for (int i = 0; i < 4; i++)
        af[i] = *(const bf16x8*)(ob + (i*16 + l15)*64 + (((kk<<2)+quad) ^ sw)*8);
      #pragma unroll
      for (int j = 0; j < 3; j++){
        bf16x8 bfr = *(const bf16x8*)(projwb + (long)(wave*48 + j*16 + l15)*384
                                      + it*64 + (kk*4 + quad)*8);
        #pragma unroll
        for (int i = 0; i < 4; i++)
          acc[i][j] = MFMA16(af[i], bfr, acc[i][j]);
      }
    }
    // no trailing barrier: next iter writes oS[(it+1)&1]; writes to THIS buf
    // recur only at it+2, after barrier B_{it+1} which follows all reads here.
  }

  // epilogue: f32 token-major
  #pragma unroll
  for (int j = 0; j < 3; j++){
    int col = wave*48 + j*16 + l15;
    float bv = proj_b[col];
    #pragma unroll
    for (int i = 0; i < 4; i++){
      long row0 = (long)b*8192 + t0 + i*16 + quad*4;
      #pragma unroll
      for (int r = 0; r < 4; r++)
        out[(row0 + r)*384 + col] = acc[i][j][r] + bv;
    }
  }
}

extern "C" void kernel_launch(void* const* d_in, const int* in_sizes, int n_in,
                              void* d_out, int out_size, void* d_ws, size_t ws_size,
                              hipStream_t stream)
{
  const float* pos      = (const float*)d_in[0];
  const float* feat     = (const float*)d_in[1];
  const int* member_idx = (const int*)d_in[2];
  const int* batch_idx  = (const int*)d_in[3];
  const float* qkv_w    = (const float*)d_in[4];
  const float* qkv_b    = (const float*)d_in[5];
  const float* pos_w    = (const float*)d_in[6];
  const float* pos_b    = (const float*)d_in[7];
  const float* proj_w   = (const float*)d_in[8];
  const float* proj_b   = (const float*)d_in[9];
  float* out = (float*)d_out;

  char* ws = (char*)d_ws;
  float* pmax           = (float*)ws;                       // 8 B
  float* pm             = (float*)(ws + 256);               // 8 KB
  unsigned short* fm    = (unsigned short*)(ws + 8704);     // 1024x384 bf16
  unsigned short* kh    = (unsigned short*)(ws + 795136);   // 4x12x256x32 bf16
  unsigned short* vt    = (unsigned short*)(ws + 1581568);  // 4x12x32x256 bf16
  unsigned short* wt    = (unsigned short*)(ws + 2368000);  // 4x12x256 bf16
  unsigned short* q_s   = (unsigned short*)(ws + 2417152);  // 48x8192x32 bf16 (head-major)
  unsigned short* qkvwb = (unsigned short*)(ws + 52748800); // 1152x384 bf16
  unsigned short* projwb= (unsigned short*)(ws + 53633536); // 384x384 bf16
  unsigned short* featb = (unsigned short*)(ws + 53928448); // 32768x384 bf16 (25.2 MB)

  hipMemsetAsync(pmax, 0, 8, stream);
  prep_means_kernel<<<1494, 192, 0, stream>>>(pos, (unsigned*)pmax, qkv_w, qkvwb,
                                              proj_w, projwb, feat, member_idx,
                                              batch_idx, fm, pm, featb);
  // kv GEMM (96 blocks, incl. wt fold) + 512 q-tiles in one 512-block launch
  kvq_kernel<<<512, 512, 0, stream>>>(fm, featb, qkvwb, qkv_b, pm, pmax, pos_w, pos_b,
                                      kh, vt, wt, q_s,
                                      0.17677669529663687f * 1.44269504088896340f);
  // fused attention + output projection (direct-L2 K/V, oS-only LDS)
  attnproj_kernel<<<512, 512, 0, stream>>>(q_s, kh, vt, wt, projwb, proj_b, out);
}

// Round 13
// 190.093 us; speedup vs baseline: 1.1296x; 1.1296x over previous
//
#include <hip/hip_runtime.h>

typedef __attribute__((ext_vector_type(8))) short bf16x8;
typedef __attribute__((ext_vector_type(4))) float f32x4;

#define MFMA16(a,b,c) __builtin_amdgcn_mfma_f32_16x16x32_bf16((a),(b),(c),0,0,0)

__device__ __forceinline__ float b2f(unsigned short u){
  union { unsigned u; float f; } x; x.u = ((unsigned)u) << 16; return x.f;
}
__device__ __forceinline__ unsigned short f2b(float f){
  union { float f; unsigned u; } x; x.f = f;
  unsigned r = x.u + 0x7FFFu + ((x.u >> 16) & 1u);
  return (unsigned short)(r >> 16);
}
__device__ __forceinline__ unsigned pk_rne(float a, float b){
  unsigned ua = __float_as_uint(a), ub = __float_as_uint(b);
  ua += 0x7FFFu + ((ua >> 16) & 1u);
  ub += 0x7FFFu + ((ub >> 16) & 1u);
  return __builtin_amdgcn_perm(ub, ua, 0x07060302u);
}
__device__ __forceinline__ unsigned pk_trunc(float a, float b){
  return __builtin_amdgcn_perm(__float_as_uint(b), __float_as_uint(a), 0x07060302u);
}
__device__ __forceinline__ bf16x8 mk8(unsigned a, unsigned b, unsigned c, unsigned d){
  union { uint4 u; bf16x8 h; } x; x.u = make_uint4(a,b,c,d); return x.h;
}
// cluster-index bit rotation so register Sᵀ fragments align with PV's B-operand k-slots
__device__ __forceinline__ int permp(int cl){
  return (cl & 0xE0) | (((cl >> 2) & 3) << 3) | (((cl >> 4) & 1) << 2) | (cl & 3);
}

typedef __attribute__((address_space(3))) unsigned int lds_u32;
typedef const __attribute__((address_space(1))) unsigned int glb_u32;
__device__ __forceinline__ void gl_lds16(const void* g, void* l){
  __builtin_amdgcn_global_load_lds((glb_u32*)g, (lds_u32*)l, 16, 0, 0);
}

// ---------------- merged prep + cluster means ----------------
__global__ __launch_bounds__(192) void prep_means_kernel(
    const float* __restrict__ pos, unsigned* __restrict__ pmax,
    const float* __restrict__ qkv_w, unsigned short* __restrict__ qkvwb,
    const float* __restrict__ proj_w, unsigned short* __restrict__ projwb,
    const float* __restrict__ feat,
    const int* __restrict__ member_idx, const int* __restrict__ batch_idx,
    unsigned short* __restrict__ fm, float* __restrict__ pm,
    unsigned short* __restrict__ featb)
{
  int bid = blockIdx.x, t = threadIdx.x;
  if (bid < 1024){
    int g = t / 96, tl = t - g*96;
    int z = bid;
    __shared__ int bases[32];
    __shared__ float4 part[96];
    if (t < 32) bases[t] = batch_idx[z*32 + t]*8192 + member_idx[z*32 + t];
    __syncthreads();
    // pos mean: one wave-load + tree reduce on lanes 0..31
    if (t < 32){
      float2 pp = ((const float2*)pos)[bases[t]];
      #pragma unroll
      for (int off = 16; off >= 1; off >>= 1){
        pp.x += __shfl_xor(pp.x, off, 32);
        pp.y += __shfl_xor(pp.y, off, 32);
      }
      if (t == 0){ pm[z*2] = pp.x*(1.f/32.f); pm[z*2+1] = pp.y*(1.f/32.f); }
    }
    // feat: 16 gather loads in flight, then stores + accumulate
    float4 v[16]; int rows[16];
    const float4* f4 = (const float4*)feat;
    #pragma unroll
    for (int m = 0; m < 16; m++){
      rows[m] = bases[g*16 + m];
      v[m] = f4[(long)rows[m]*96 + tl];
    }
    float4 a = {0.f,0.f,0.f,0.f};
    #pragma unroll
    for (int m = 0; m < 16; m++){
      *(uint2*)(featb + (long)rows[m]*384 + tl*4) =
          make_uint2(pk_rne(v[m].x, v[m].y), pk_rne(v[m].z, v[m].w));
      a.x += v[m].x; a.y += v[m].y; a.z += v[m].z; a.w += v[m].w;
    }
    if (g == 1) part[tl] = a;
    __syncthreads();
    if (g == 0){
      float4 b = part[tl];
      a.x += b.x; a.y += b.y; a.z += b.z; a.w += b.w;
      unsigned d0 = pk_rne(a.x*(1.f/32.f), a.y*(1.f/32.f));
      unsigned d1 = pk_rne(a.z*(1.f/32.f), a.w*(1.f/32.f));
      *(uint2*)(fm + (long)z*384 + tl*4) = make_uint2(d0, d1);
    }
  } else if (bid < 1408){
    int u = (bid - 1024)*192 + t;     // [0, 73728)
    const float* in; unsigned short* o; long i;
    if (u < 55296){ in = qkv_w;  o = qkvwb;  i = u; }
    else          { in = proj_w; o = projwb; i = u - 55296; }
    const float4* p = (const float4*)(in + i*8);
    float4 a = p[0], b = p[1];
    *(uint4*)(o + i*8) = make_uint4(pk_rne(a.x,a.y), pk_rne(a.z,a.w),
                                    pk_rne(b.x,b.y), pk_rne(b.z,b.w));
  } else {
    int i = (bid - 1408)*192 + t;
    if (i < 16384){
      float4 v = ((const float4*)pos)[i];
      float m0 = fmaxf(v.x, v.z), m1 = fmaxf(v.y, v.w);
      #pragma unroll
      for (int off = 32; off >= 1; off >>= 1){
        m0 = fmaxf(m0, __shfl_xor(m0, off, 64));
        m1 = fmaxf(m1, __shfl_xor(m1, off, 64));
      }
      if ((t & 63) == 0){
        atomicMax(&pmax[0], __float_as_uint(m0));
        atomicMax(&pmax[1], __float_as_uint(m1));
      }
    }
  }
}

// ---------------- merged kv-GEMM + wt + q-GEMM, 512 blocks ----------------
__global__ __launch_bounds__(512) void kvq_kernel(
    const unsigned short* __restrict__ fm,     // (1024,384) bf16 cluster means
    const unsigned short* __restrict__ featb,  // (32768,384) bf16
    const unsigned short* __restrict__ qkvwb,  // (1152,384) bf16; rows 0..383 = Wq
    const float* __restrict__ qkv_b,           // (1152)
    const float* __restrict__ pm, const float* __restrict__ pmaxf,
    const float* __restrict__ pos_w, const float* __restrict__ pos_b,
    unsigned short* __restrict__ kh, unsigned short* __restrict__ vt,
    unsigned short* __restrict__ wt,
    unsigned short* __restrict__ q_s, float q_scale)
{
  __shared__ unsigned short As[64*64];    // 8 KB
  __shared__ unsigned short Ws[384*64];   // 48 KB
  __shared__ unsigned short wtS[256];
  const int K = 384;
  int tid = threadIdx.x;
  int lane = tid & 63, wave = tid >> 6;
  int l15 = lane & 15, quad = lane >> 4;
  int sw = l15 & 7;
  int srow = tid >> 3, sc8 = tid & 7;     // 512 thr: srow 0..63

  int qtile;
  if (blockIdx.x < 96){
    // ================= kv GEMM =================
    int mt = blockIdx.x / 6, nt = blockIdx.x - mt*6;
    int m0 = mt << 6, n0 = nt << 7;
    int b = m0 >> 8, cl0 = m0 & 255;
    const unsigned short* W = qkvwb + 384*384;
    // wt prologue: this block's 4 heads x 64 clusters (bit-identical to old bias_kernel)
    if (nt >= 3 && tid < 256){
      int lh = tid >> 6, lc = tid & 63;
      int h = ((n0 - 384) >> 5) + lh;
      int cl = cl0 + lc;
      float p0 = pm[(b*256 + cl)*2]   / pmaxf[0];
      float p1 = pm[(b*256 + cl)*2+1] / pmaxf[1];
      float bias = p0*pos_w[h*2] + p1*pos_w[h*2+1] + pos_b[h];
      unsigned short wv = f2b(exp2f(bias * 1.44269504088896340f));
      wtS[lh*64 + lc] = wv;
      wt[(((long)(b*12 + h)) << 8) + permp(cl)] = wv;
    }
    int wr = (wave >> 2) << 5, wc = (wave & 3) << 5;
    f32x4 acc[2][2];
    #pragma unroll
    for (int i = 0; i < 2; i++)
      #pragma unroll
      for (int j = 0; j < 2; j++) acc[i][j] = (f32x4){0.f,0.f,0.f,0.f};

    for (int k0 = 0; k0 < K; k0 += 64){
      __syncthreads();
      int gc8 = sc8 ^ (srow & 7);
      gl_lds16(fm + (long)(m0+srow)*K + k0 + gc8*8, As + wave*512);
      #pragma unroll
      for (int it = 0; it < 2; it++){
        int r = it*64 + srow;
        int g2 = sc8 ^ (r & 7);
        gl_lds16(W + (long)(n0+r)*K + k0 + g2*8, Ws + it*4096 + wave*512);
      }
      __syncthreads();
      #pragma unroll
      for (int kk = 0; kk < 2; kk++){
        bf16x8 af[2], bfr[2];
        #pragma unroll
        for (int i = 0; i < 2; i++)
          af[i] = *(const bf16x8*)(As + (wr + i*16 + l15)*64 + (((kk<<2)+quad) ^ sw)*8);
        #pragma unroll
        for (int j = 0; j < 2; j++)
          bfr[j] = *(const bf16x8*)(Ws + (wc + j*16 + l15)*64 + (((kk<<2)+quad) ^ sw)*8);
        #pragma unroll
        for (int i = 0; i < 2; i++)
          #pragma unroll
          for (int j = 0; j < 2; j++)
            acc[i][j] = MFMA16(af[i], bfr[j], acc[i][j]);
      }
    }

    #pragma unroll
    for (int j = 0; j < 2; j++){
      int col = n0 + wc + j*16 + l15;
      float bv = qkv_b[384 + col];
      #pragma unroll
      for (int i = 0; i < 2; i++){
        #pragma unroll
        for (int r = 0; r < 4; r++){
          float v = acc[i][j][r] + bv;
          int lr = wr + i*16 + quad*4 + r;     // local row 0..63
          int cl = cl0 + lr;
          if (col < 384){
            int h = col >> 5, ch = col & 31;
            kh[((((long)b*12 + h)*256 + cl)*32) + ch] = f2b(v);
          } else {
            int cn = col - 384;
            int h = cn >> 5, ch = cn & 31;
            int pp = permp(cl);
            int c8 = (pp >> 3) ^ (ch & 7);
            float w = b2f(wtS[(wave & 3)*64 + lr]);
            vt[(((long)b*12 + h)*32 + ch)*256 + c8*8 + (pp & 7)] = f2b(v * w);
          }
        }
      }
    }
    qtile = 416 + blockIdx.x;
  } else {
    qtile = blockIdx.x - 96;
  }

  // ================= q GEMM (single-buffer, 2 blocks/CU structure) =================
  {
    int m0 = qtile << 6;
    f32x4 acc[4][3];
    #pragma unroll
    for (int i = 0; i < 4; i++)
      #pragma unroll
      for (int j = 0; j < 3; j++) acc[i][j] = (f32x4){0.f,0.f,0.f,0.f};

    for (int k0 = 0; k0 < K; k0 += 64){
      __syncthreads();
      int gc8 = sc8 ^ (srow & 7);
      gl_lds16(featb + (long)(m0+srow)*K + k0 + gc8*8, As + wave*512);
      #pragma unroll
      for (int it = 0; it < 6; it++){
        int r = it*64 + srow;
        int g2 = sc8 ^ (r & 7);
        gl_lds16(qkvwb + (long)r*K + k0 + g2*8, Ws + it*4096 + wave*512);
      }
      __syncthreads();
      #pragma unroll
      for (int kk = 0; kk < 2; kk++){
        bf16x8 af[4];
        #pragma unroll
        for (int i = 0; i < 4; i++)
          af[i] = *(const bf16x8*)(As + (i*16 + l15)*64 + (((kk<<2)+quad) ^ sw)*8);
        #pragma unroll
        for (int j = 0; j < 3; j++){
          bf16x8 bfr = *(const bf16x8*)(Ws + (wave*48 + j*16 + l15)*64 + (((kk<<2)+quad) ^ sw)*8);
          #pragma unroll
          for (int i = 0; i < 4; i++)
            acc[i][j] = MFMA16(af[i], bfr, acc[i][j]);
        }
      }
    }

    #pragma unroll
    for (int j = 0; j < 3; j++){
      int col = wave*48 + j*16 + l15;
      float bv = qkv_b[col];
      #pragma unroll
      for (int i = 0; i < 4; i++){
        int row0 = m0 + i*16 + quad*4;
        #pragma unroll
        for (int r = 0; r < 4; r++){
          float v = (acc[i][j][r] + bv) * q_scale;
          int row = row0 + r;
          int bb = row >> 13, tok = row & 8191;
          q_s[((((long)(bb*12 + (col >> 5))) << 13) + tok)*32 + (col & 31)] = f2b(v);
        }
      }
    }
  }
}

// ---------------- FUSED attention + proj: 4-wave blocks, double-buffered stage ----------------
// block = (b, 64 tokens), 256 thr / 4 waves, 512 blocks = 2 blocks/CU (75 KB LDS).
// 12 SINGLE-HEAD iterations; per iter the stage of head it+1 (32.5 KB, the half-
// size footprint that makes double-buffering fit at 2 blocks/CU) is issued BEFORE
// attn(it) and lands at the one barrier per iteration -> stage latency hides under
// the attn+proj compute (r7-r11's serial stage->drain->barrier was the stall; r12
// proved direct-L2 is latency-bound, so LDS reads stay).
// Hazards: stage(it+1) writes buf^1 while attn(it) reads buf; stage(it+2) writes
// buf only after barrier(it) which follows all attn(it) reads; oS double-buffered
// so proj(it) reads race-free vs oS-write(it+1).
// oS padded to stride 40 shorts (80 B = 5x16 B): aligned b128 reads, spread banks.
// Head accumulation order == r7's (it,kk) order -> bit-identical output.
__global__ __launch_bounds__(256, 2) void attnproj_kernel(
    const unsigned short* __restrict__ qhm,    // (B*H,8192,32) bf16, scale*log2e folded
    const unsigned short* __restrict__ kh,     // (B,H,256,32) bf16, linear
    const unsigned short* __restrict__ vt,     // (B,H,32,256) bf16, permp-packed, w-folded
    const unsigned short* __restrict__ wt,     // (B*H,256) bf16, permp'd
    const unsigned short* __restrict__ projwb, // (384,384) bf16
    const float* __restrict__ proj_b,
    float* __restrict__ out)                   // (B*8192,384) f32
{
  __shared__ unsigned short keyS[2][8192];     // 2 x 16 KB: [head][256][32]
  __shared__ unsigned short vTS[2][8192];      // 2 x 16 KB: [head][32][256] packed
  __shared__ unsigned short wS[2][256];        // 2 x 0.5 KB
  __shared__ unsigned short oS[2][64*40];      // 2 x 5 KB: [tok][ch], stride 40

  int bid = blockIdx.x;
  int b = bid >> 7;
  int t0 = (bid & 127) << 6;
  int tid = threadIdx.x, lane = tid & 63, wave = tid >> 6;   // 4 waves
  int l15 = lane & 15, quad = lane >> 4;
  int sw = l15 & 7;
  long bbase = (long)b*12;

  f32x4 acc[4][6];
  #pragma unroll
  for (int i = 0; i < 4; i++)
    #pragma unroll
    for (int j = 0; j < 6; j++) acc[i][j] = (f32x4){0.f,0.f,0.f,0.f};

  // stage one head (16 KB K + 16 KB V + 0.5 KB w), linear coalesced
  auto stage = [&](int buf, int h){
    const unsigned short* ks = kh + (bbase + h)*8192;
    const unsigned short* vs = vt + (bbase + h)*8192;
    #pragma unroll
    for (int p = 0; p < 4; p++){
      gl_lds16(ks + p*2048 + tid*8, &keyS[buf][p*2048 + wave*512]);
      gl_lds16(vs + p*2048 + tid*8, &vTS[buf][p*2048 + wave*512]);
    }
    if (tid < 32) gl_lds16(wt + (bbase + h)*256 + lane*8, &wS[buf][0]);
  };

  stage(0, 0);
  __syncthreads();                              // stage(0) landed

  for (int it = 0; it < 12; ++it){
    int buf = it & 1;
    if (it < 11) stage(buf ^ 1, it + 1);        // in flight under attn+proj

    long bh = bbase + it;
    bf16x8 aq = *(const bf16x8*)(qhm + (bh*8192 + t0 + wave*16 + l15)*32 + quad*8);

    const unsigned short* kb = &keyS[buf][0];
    const unsigned short* vb = &vTS[buf][0];
    const unsigned short* wb = &wS[buf][0];

    f32x4 o0 = {0.f,0.f,0.f,0.f}, o1 = {0.f,0.f,0.f,0.f}, os = {0.f,0.f,0.f,0.f};
    #pragma unroll
    for (int ks8 = 0; ks8 < 8; ks8++){
      bf16x8 bk0 = *(const bf16x8*)(kb + (32*ks8 + l15)*32 + quad*8);
      bf16x8 bk1 = *(const bf16x8*)(kb + (32*ks8 + 16 + l15)*32 + quad*8);
      const f32x4 z4 = {0.f,0.f,0.f,0.f};
      f32x4 s0 = MFMA16(bk0, aq, z4);
      f32x4 s1 = MFMA16(bk1, aq, z4);
      #pragma unroll
      for (int c = 0; c < 4; c++){ s0[c] = exp2f(s0[c]); s1[c] = exp2f(s1[c]); }
      bf16x8 pf = mk8(pk_trunc(s0[0],s0[1]), pk_trunc(s0[2],s0[3]),
                      pk_trunc(s1[0],s1[1]), pk_trunc(s1[2],s1[3]));
      int c8 = (4*ks8 + quad) ^ sw;
      bf16x8 a0 = *(const bf16x8*)(vb + l15*256      + c8*8);
      bf16x8 a1 = *(const bf16x8*)(vb + (16+l15)*256 + c8*8);
      bf16x8 wf = *(const bf16x8*)(wb + ks8*32 + quad*8);
      o0 = MFMA16(a0, pf, o0);
      o1 = MFMA16(a1, pf, o1);
      os = MFMA16(wf, pf, os);
    }

    // normalize + store O tile [64 tok][32 ch] (stride 40) into oS[buf]
    // (bf16-rounded at the same point as the old ao write -> bit-identical)
    float inv = 1.f / os[0];
    unsigned short* ob = &oS[buf][0];
    int row = wave*16 + l15;
    *(uint2*)(ob + row*40 + quad*4) =
        make_uint2(pk_rne(o0[0]*inv, o0[1]*inv), pk_rne(o0[2]*inv, o0[3]*inv));
    *(uint2*)(ob + row*40 + 16 + quad*4) =
        make_uint2(pk_rne(o1[0]*inv, o1[1]*inv), pk_rne(o1[2]*inv, o1[3]*inv));
    __syncthreads();                            // oS(it) visible; stage(it+1) landed

    // proj accumulate: BK=32 (head it's channels); B direct from L2-resident projwb
    bf16x8 af[4];
    #pragma unroll
    for (int i = 0; i < 4; i++)
      af[i] = *(const bf16x8*)(ob + (i*16 + l15)*40 + quad*8);
    #pragma unroll
    for (int j = 0; j < 6; j++){
      int col = wave*96 + j*16 + l15;
      bf16x8 bfr = *(const bf16x8*)(projwb + (long)col*384 + it*32 + quad*8);
      #pragma unroll
      for (int i = 0; i < 4; i++)
        acc[i][j] = MFMA16(af[i], bfr, acc[i][j]);
    }
    // no trailing barrier: next iter writes oS[buf^1]/keyS[buf^1]; writes to THIS
    // buf recur at it+2, after barrier(it+1), which follows all reads here.
  }

  // epilogue: f32 token-major
  #pragma unroll
  for (int j = 0; j < 6; j++){
    int col = wave*96 + j*16 + l15;
    float bv = proj_b[col];
    #pragma unroll
    for (int i = 0; i < 4; i++){
      long row0 = (long)b*8192 + t0 + i*16 + quad*4;
      #pragma unroll
      for (int r = 0; r < 4; r++)
        out[(row0 + r)*384 + col] = acc[i][j][r] + bv;
    }
  }
}

extern "C" void kernel_launch(void* const* d_in, const int* in_sizes, int n_in,
                              void* d_out, int out_size, void* d_ws, size_t ws_size,
                              hipStream_t stream)
{
  const float* pos      = (const float*)d_in[0];
  const float* feat     = (const float*)d_in[1];
  const int* member_idx = (const int*)d_in[2];
  const int* batch_idx  = (const int*)d_in[3];
  const float* qkv_w    = (const float*)d_in[4];
  const float* qkv_b    = (const float*)d_in[5];
  const float* pos_w    = (const float*)d_in[6];
  const float* pos_b    = (const float*)d_in[7];
  const float* proj_w   = (const float*)d_in[8];
  const float* proj_b   = (const float*)d_in[9];
  float* out = (float*)d_out;

  char* ws = (char*)d_ws;
  float* pmax           = (float*)ws;                       // 8 B
  float* pm             = (float*)(ws + 256);               // 8 KB
  unsigned short* fm    = (unsigned short*)(ws + 8704);     // 1024x384 bf16
  unsigned short* kh    = (unsigned short*)(ws + 795136);   // 4x12x256x32 bf16
  unsigned short* vt    = (unsigned short*)(ws + 1581568);  // 4x12x32x256 bf16
  unsigned short* wt    = (unsigned short*)(ws + 2368000);  // 4x12x256 bf16
  unsigned short* q_s   = (unsigned short*)(ws + 2417152);  // 48x8192x32 bf16 (head-major)
  unsigned short* qkvwb = (unsigned short*)(ws + 52748800); // 1152x384 bf16
  unsigned short* projwb= (unsigned short*)(ws + 53633536); // 384x384 bf16
  unsigned short* featb = (unsigned short*)(ws + 53928448); // 32768x384 bf16 (25.2 MB)

  hipMemsetAsync(pmax, 0, 8, stream);
  prep_means_kernel<<<1494, 192, 0, stream>>>(pos, (unsigned*)pmax, qkv_w, qkvwb,
                                              proj_w, projwb, feat, member_idx,
                                              batch_idx, fm, pm, featb);
  // kv GEMM (96 blocks, incl. wt fold) + 512 q-tiles in one 512-block launch
  kvq_kernel<<<512, 512, 0, stream>>>(fm, featb, qkvwb, qkv_b, pm, pmax, pos_w, pos_b,
                                      kh, vt, wt, q_s,
                                      0.17677669529663687f * 1.44269504088896340f);
  // fused attention + output projection (4-wave blocks, double-buffered stage)
  attnproj_kernel<<<512, 256, 0, stream>>>(q_s, kh, vt, wt, projwb, proj_b, out);
}

// Round 14
// 186.057 us; speedup vs baseline: 1.1541x; 1.0217x over previous
//
#include <hip/hip_runtime.h>

typedef __attribute__((ext_vector_type(8))) short bf16x8;
typedef __attribute__((ext_vector_type(4))) float f32x4;

#define MFMA16(a,b,c) __builtin_amdgcn_mfma_f32_16x16x32_bf16((a),(b),(c),0,0,0)

__device__ __forceinline__ float b2f(unsigned short u){
  union { unsigned u; float f; } x; x.u = ((unsigned)u) << 16; return x.f;
}
__device__ __forceinline__ unsigned short f2b(float f){
  union { float f; unsigned u; } x; x.f = f;
  unsigned r = x.u + 0x7FFFu + ((x.u >> 16) & 1u);
  return (unsigned short)(r >> 16);
}
__device__ __forceinline__ unsigned pk_rne(float a, float b){
  unsigned ua = __float_as_uint(a), ub = __float_as_uint(b);
  ua += 0x7FFFu + ((ua >> 16) & 1u);
  ub += 0x7FFFu + ((ub >> 16) & 1u);
  return __builtin_amdgcn_perm(ub, ua, 0x07060302u);
}
__device__ __forceinline__ unsigned pk_trunc(float a, float b){
  return __builtin_amdgcn_perm(__float_as_uint(b), __float_as_uint(a), 0x07060302u);
}
__device__ __forceinline__ bf16x8 mk8(unsigned a, unsigned b, unsigned c, unsigned d){
  union { uint4 u; bf16x8 h; } x; x.u = make_uint4(a,b,c,d); return x.h;
}
// cluster-index bit rotation so register Sᵀ fragments align with PV's B-operand k-slots
__device__ __forceinline__ int permp(int cl){
  return (cl & 0xE0) | (((cl >> 2) & 3) << 3) | (((cl >> 4) & 1) << 2) | (cl & 3);
}

typedef __attribute__((address_space(3))) unsigned int lds_u32;
typedef const __attribute__((address_space(1))) unsigned int glb_u32;
__device__ __forceinline__ void gl_lds16(const void* g, void* l){
  __builtin_amdgcn_global_load_lds((glb_u32*)g, (lds_u32*)l, 16, 0, 0);
}

// ---------------- merged prep + cluster means ----------------
__global__ __launch_bounds__(192) void prep_means_kernel(
    const float* __restrict__ pos, unsigned* __restrict__ pmax,
    const float* __restrict__ qkv_w, unsigned short* __restrict__ qkvwb,
    const float* __restrict__ proj_w, unsigned short* __restrict__ projwb,
    const float* __restrict__ feat,
    const int* __restrict__ member_idx, const int* __restrict__ batch_idx,
    unsigned short* __restrict__ fm, float* __restrict__ pm,
    unsigned short* __restrict__ featb)
{
  int bid = blockIdx.x, t = threadIdx.x;
  if (bid < 1024){
    int g = t / 96, tl = t - g*96;
    int z = bid;
    __shared__ int bases[32];
    __shared__ float4 part[96];
    if (t < 32) bases[t] = batch_idx[z*32 + t]*8192 + member_idx[z*32 + t];
    __syncthreads();
    // pos mean: one wave-load + tree reduce on lanes 0..31
    if (t < 32){
      float2 pp = ((const float2*)pos)[bases[t]];
      #pragma unroll
      for (int off = 16; off >= 1; off >>= 1){
        pp.x += __shfl_xor(pp.x, off, 32);
        pp.y += __shfl_xor(pp.y, off, 32);
      }
      if (t == 0){ pm[z*2] = pp.x*(1.f/32.f); pm[z*2+1] = pp.y*(1.f/32.f); }
    }
    // feat: 16 gather loads in flight, then stores + accumulate
    float4 v[16]; int rows[16];
    const float4* f4 = (const float4*)feat;
    #pragma unroll
    for (int m = 0; m < 16; m++){
      rows[m] = bases[g*16 + m];
      v[m] = f4[(long)rows[m]*96 + tl];
    }
    float4 a = {0.f,0.f,0.f,0.f};
    #pragma unroll
    for (int m = 0; m < 16; m++){
      *(uint2*)(featb + (long)rows[m]*384 + tl*4) =
          make_uint2(pk_rne(v[m].x, v[m].y), pk_rne(v[m].z, v[m].w));
      a.x += v[m].x; a.y += v[m].y; a.z += v[m].z; a.w += v[m].w;
    }
    if (g == 1) part[tl] = a;
    __syncthreads();
    if (g == 0){
      float4 b = part[tl];
      a.x += b.x; a.y += b.y; a.z += b.z; a.w += b.w;
      unsigned d0 = pk_rne(a.x*(1.f/32.f), a.y*(1.f/32.f));
      unsigned d1 = pk_rne(a.z*(1.f/32.f), a.w*(1.f/32.f));
      *(uint2*)(fm + (long)z*384 + tl*4) = make_uint2(d0, d1);
    }
  } else if (bid < 1408){
    int u = (bid - 1024)*192 + t;     // [0, 73728)
    const float* in; unsigned short* o; long i;
    if (u < 55296){ in = qkv_w;  o = qkvwb;  i = u; }
    else          { in = proj_w; o = projwb; i = u - 55296; }
    const float4* p = (const float4*)(in + i*8);
    float4 a = p[0], b = p[1];
    *(uint4*)(o + i*8) = make_uint4(pk_rne(a.x,a.y), pk_rne(a.z,a.w),
                                    pk_rne(b.x,b.y), pk_rne(b.z,b.w));
  } else {
    int i = (bid - 1408)*192 + t;
    if (i < 16384){
      float4 v = ((const float4*)pos)[i];
      float m0 = fmaxf(v.x, v.z), m1 = fmaxf(v.y, v.w);
      #pragma unroll
      for (int off = 32; off >= 1; off >>= 1){
        m0 = fmaxf(m0, __shfl_xor(m0, off, 64));
        m1 = fmaxf(m1, __shfl_xor(m1, off, 64));
      }
      if ((t & 63) == 0){
        atomicMax(&pmax[0], __float_as_uint(m0));
        atomicMax(&pmax[1], __float_as_uint(m1));
      }
    }
  }
}

// ---------------- merged kv-GEMM + wt + q-GEMM, 512 blocks ----------------
// kh is written PRE-SWIZZLED: within each cluster row, 16B unit
// unit' = (ch>>3) ^ ((cl>>1)&3). attnproj stages kh LINEARLY and applies the
// same XOR on the LDS read -> conflict-reduced K-reads with linear staging.
__global__ __launch_bounds__(512) void kvq_kernel(
    const unsigned short* __restrict__ fm,     // (1024,384) bf16 cluster means
    const unsigned short* __restrict__ featb,  // (32768,384) bf16
    const unsigned short* __restrict__ qkvwb,  // (1152,384) bf16; rows 0..383 = Wq
    const float* __restrict__ qkv_b,           // (1152)
    const float* __restrict__ pm, const float* __restrict__ pmaxf,
    const float* __restrict__ pos_w, const float* __restrict__ pos_b,
    unsigned short* __restrict__ kh, unsigned short* __restrict__ vt,
    unsigned short* __restrict__ wt,
    unsigned short* __restrict__ q_s, float q_scale)
{
  __shared__ unsigned short As[64*64];    // 8 KB
  __shared__ unsigned short Ws[384*64];   // 48 KB
  __shared__ unsigned short wtS[256];
  const int K = 384;
  int tid = threadIdx.x;
  int lane = tid & 63, wave = tid >> 6;
  int l15 = lane & 15, quad = lane >> 4;
  int sw = l15 & 7;
  int srow = tid >> 3, sc8 = tid & 7;     // 512 thr: srow 0..63

  int qtile;
  if (blockIdx.x < 96){
    // ================= kv GEMM =================
    int mt = blockIdx.x / 6, nt = blockIdx.x - mt*6;
    int m0 = mt << 6, n0 = nt << 7;
    int b = m0 >> 8, cl0 = m0 & 255;
    const unsigned short* W = qkvwb + 384*384;
    // wt prologue: this block's 4 heads x 64 clusters (bit-identical to old bias_kernel)
    if (nt >= 3 && tid < 256){
      int lh = tid >> 6, lc = tid & 63;
      int h = ((n0 - 384) >> 5) + lh;
      int cl = cl0 + lc;
      float p0 = pm[(b*256 + cl)*2]   / pmaxf[0];
      float p1 = pm[(b*256 + cl)*2+1] / pmaxf[1];
      float bias = p0*pos_w[h*2] + p1*pos_w[h*2+1] + pos_b[h];
      unsigned short wv = f2b(exp2f(bias * 1.44269504088896340f));
      wtS[lh*64 + lc] = wv;
      wt[(((long)(b*12 + h)) << 8) + permp(cl)] = wv;
    }
    int wr = (wave >> 2) << 5, wc = (wave & 3) << 5;
    f32x4 acc[2][2];
    #pragma unroll
    for (int i = 0; i < 2; i++)
      #pragma unroll
      for (int j = 0; j < 2; j++) acc[i][j] = (f32x4){0.f,0.f,0.f,0.f};

    for (int k0 = 0; k0 < K; k0 += 64){
      __syncthreads();
      int gc8 = sc8 ^ (srow & 7);
      gl_lds16(fm + (long)(m0+srow)*K + k0 + gc8*8, As + wave*512);
      #pragma unroll
      for (int it = 0; it < 2; it++){
        int r = it*64 + srow;
        int g2 = sc8 ^ (r & 7);
        gl_lds16(W + (long)(n0+r)*K + k0 + g2*8, Ws + it*4096 + wave*512);
      }
      __syncthreads();
      #pragma unroll
      for (int kk = 0; kk < 2; kk++){
        bf16x8 af[2], bfr[2];
        #pragma unroll
        for (int i = 0; i < 2; i++)
          af[i] = *(const bf16x8*)(As + (wr + i*16 + l15)*64 + (((kk<<2)+quad) ^ sw)*8);
        #pragma unroll
        for (int j = 0; j < 2; j++)
          bfr[j] = *(const bf16x8*)(Ws + (wc + j*16 + l15)*64 + (((kk<<2)+quad) ^ sw)*8);
        #pragma unroll
        for (int i = 0; i < 2; i++)
          #pragma unroll
          for (int j = 0; j < 2; j++)
            acc[i][j] = MFMA16(af[i], bfr[j], acc[i][j]);
      }
    }

    #pragma unroll
    for (int j = 0; j < 2; j++){
      int col = n0 + wc + j*16 + l15;
      float bv = qkv_b[384 + col];
      #pragma unroll
      for (int i = 0; i < 2; i++){
        #pragma unroll
        for (int r = 0; r < 4; r++){
          float v = acc[i][j][r] + bv;
          int lr = wr + i*16 + quad*4 + r;     // local row 0..63
          int cl = cl0 + lr;
          if (col < 384){
            int h = col >> 5, ch = col & 31;
            int cu = ((ch >> 3) ^ ((cl >> 1) & 3));   // pre-swizzled 16B unit
            kh[((((long)b*12 + h)*256 + cl)*32) + cu*8 + (ch & 7)] = f2b(v);
          } else {
            int cn = col - 384;
            int h = cn >> 5, ch = cn & 31;
            int pp = permp(cl);
            int c8 = (pp >> 3) ^ (ch & 7);
            float w = b2f(wtS[(wave & 3)*64 + lr]);
            vt[(((long)b*12 + h)*32 + ch)*256 + c8*8 + (pp & 7)] = f2b(v * w);
          }
        }
      }
    }
    qtile = 416 + blockIdx.x;
  } else {
    qtile = blockIdx.x - 96;
  }

  // ================= q GEMM (single-buffer, 2 blocks/CU structure) =================
  {
    int m0 = qtile << 6;
    f32x4 acc[4][3];
    #pragma unroll
    for (int i = 0; i < 4; i++)
      #pragma unroll
      for (int j = 0; j < 3; j++) acc[i][j] = (f32x4){0.f,0.f,0.f,0.f};

    for (int k0 = 0; k0 < K; k0 += 64){
      __syncthreads();
      int gc8 = sc8 ^ (srow & 7);
      gl_lds16(featb + (long)(m0+srow)*K + k0 + gc8*8, As + wave*512);
      #pragma unroll
      for (int it = 0; it < 6; it++){
        int r = it*64 + srow;
        int g2 = sc8 ^ (r & 7);
        gl_lds16(qkvwb + (long)r*K + k0 + g2*8, Ws + it*4096 + wave*512);
      }
      __syncthreads();
      #pragma unroll
      for (int kk = 0; kk < 2; kk++){
        bf16x8 af[4];
        #pragma unroll
        for (int i = 0; i < 4; i++)
          af[i] = *(const bf16x8*)(As + (i*16 + l15)*64 + (((kk<<2)+quad) ^ sw)*8);
        #pragma unroll
        for (int j = 0; j < 3; j++){
          bf16x8 bfr = *(const bf16x8*)(Ws + (wave*48 + j*16 + l15)*64 + (((kk<<2)+quad) ^ sw)*8);
          #pragma unroll
          for (int i = 0; i < 4; i++)
            acc[i][j] = MFMA16(af[i], bfr, acc[i][j]);
        }
      }
    }

    #pragma unroll
    for (int j = 0; j < 3; j++){
      int col = wave*48 + j*16 + l15;
      float bv = qkv_b[col];
      #pragma unroll
      for (int i = 0; i < 4; i++){
        int row0 = m0 + i*16 + quad*4;
        #pragma unroll
        for (int r = 0; r < 4; r++){
          float v = (acc[i][j][r] + bv) * q_scale;
          int row = row0 + r;
          int bb = row >> 13, tok = row & 8191;
          q_s[((((long)(bb*12 + (col >> 5))) << 13) + tok)*32 + (col & 31)] = f2b(v);
        }
      }
    }
  }
}

// ---------------- FUSED attention + proj (r11 + async stage issue) ----------------
// block = (b, 64 tokens), 512 thr / 8 waves, 512 blocks = 2 blocks/CU (73 KB LDS).
// r11 structure with ONE change: stage(it+1) is issued AFTER barrier B (which
// guarantees all keyS/vTS reads of iter it are done) and BEFORE proj(it) — the
// 65 KB load train flies under proj's MFMAs + barrier-A stagger instead of being
// drained cold at loop top (r11's zero-overlap serial stage). No resource change.
// Hazards: stage(it+1) vs attn(it) reads — barrier B; vs attn(it+1) reads —
// barrier A (vmcnt drained); proj(it) oS reads all precede barrier A, oS write
// (it+1) follows it.
__global__ __launch_bounds__(512, 4) void attnproj_kernel(
    const unsigned short* __restrict__ qhm,    // (B*H,8192,32) bf16, scale*log2e folded
    const unsigned short* __restrict__ kh,     // (B,H,256,32) bf16, unit-swizzled
    const unsigned short* __restrict__ vt,     // (B,H,32,256) bf16, permp-packed, w-folded
    const unsigned short* __restrict__ wt,     // (B*H,256) bf16, permp'd
    const unsigned short* __restrict__ projwb, // (384,384) bf16
    const float* __restrict__ proj_b,
    float* __restrict__ out)                   // (B*8192,384) f32
{
  __shared__ unsigned short keyS[16384];       // 32 KB: [head][256][32], unit-swizzled
  __shared__ unsigned short vTS[16384];        // 32 KB: [head][32][256] packed
  __shared__ unsigned short oS[64*64];         // 8 KB: [tok][ch oct^sw]
  __shared__ unsigned short wS[512];           // 1 KB: [head][256]

  int bid = blockIdx.x;
  int b = bid >> 7;
  int t0 = (bid & 127) << 6;
  int tid = threadIdx.x, lane = tid & 63, wave = tid >> 6;
  int l15 = lane & 15, quad = lane >> 4;
  int sw = l15 & 7;
  int hsel = wave >> 2, ti = wave & 3;
  long bbase = (long)b*12;

  f32x4 acc[4][3];
  #pragma unroll
  for (int i = 0; i < 4; i++)
    #pragma unroll
    for (int j = 0; j < 3; j++) acc[i][j] = (f32x4){0.f,0.f,0.f,0.f};

  // stage head-pair h0,h0+1 (32 KB K + 32 KB V + 1 KB w), all LINEAR
  auto stage = [&](int h0){
    const unsigned short* ks = kh + (bbase + h0)*8192;   // 2 heads contiguous
    const unsigned short* vs = vt + (bbase + h0)*8192;
    #pragma unroll
    for (int p = 0; p < 4; p++){
      gl_lds16(ks + p*4096 + tid*8, keyS + p*4096 + wave*512);
      gl_lds16(vs + p*4096 + tid*8, vTS + p*4096 + wave*512);
    }
    if (wave == 0)
      gl_lds16(wt + (bbase + h0)*256 + lane*8, wS);
  };

  // prologue: stage(0) + q(0), drain at barrier A(0)
  stage(0);
  long qoff = (long)(t0 + ti*16 + l15)*32 + quad*8;
  bf16x8 aq = *(const bf16x8*)(qhm + (bbase + hsel)*8192*32 + qoff);
  __syncthreads();                              // A(0): stage(0) landed

  for (int it = 0; it < 6; ++it){
    const unsigned short* kb = keyS + hsel*8192;
    const unsigned short* vb = vTS  + hsel*8192;
    const unsigned short* wb = wS   + hsel*256;

    f32x4 o0 = {0.f,0.f,0.f,0.f}, o1 = {0.f,0.f,0.f,0.f}, os = {0.f,0.f,0.f,0.f};
    #pragma unroll
    for (int ks8 = 0; ks8 < 8; ks8++){
      int r0 = 32*ks8 + l15, r1 = r0 + 16;     // local K rows this k-slot
      bf16x8 bk0 = *(const bf16x8*)(kb + r0*32 + (quad ^ ((r0 >> 1) & 3))*8);
      bf16x8 bk1 = *(const bf16x8*)(kb + r1*32 + (quad ^ ((r1 >> 1) & 3))*8);
      const f32x4 z4 = {0.f,0.f,0.f,0.f};
      f32x4 s0 = MFMA16(bk0, aq, z4);
      f32x4 s1 = MFMA16(bk1, aq, z4);
      #pragma unroll
      for (int c = 0; c < 4; c++){ s0[c] = exp2f(s0[c]); s1[c] = exp2f(s1[c]); }
      bf16x8 pf = mk8(pk_trunc(s0[0],s0[1]), pk_trunc(s0[2],s0[3]),
                      pk_trunc(s1[0],s1[1]), pk_trunc(s1[2],s1[3]));
      int c8 = (4*ks8 + quad) ^ sw;
      bf16x8 a0 = *(const bf16x8*)(vb + l15*256      + c8*8);
      bf16x8 a1 = *(const bf16x8*)(vb + (16+l15)*256 + c8*8);
      bf16x8 wf = *(const bf16x8*)(wb + ks8*32 + quad*8);
      o0 = MFMA16(a0, pf, o0);
      o1 = MFMA16(a1, pf, o1);
      os = MFMA16(wf, pf, os);
    }

    // normalize + store O tile [64 tok][64 ch] bf16 with oct^sw swizzle
    // (O bf16-rounded at the same point as the old global ao write -> bit-identical)
    float inv = 1.f / os[0];
    int tokLoc = ti*16 + l15;                 // tokLoc&7 == sw
    int oct0 = hsel*4 + (quad >> 1);          // o0: ch hsel*32+quad*4..+3 ; o1: +16
    int wi = (quad & 1)*4;
    *(uint2*)(oS + tokLoc*64 + ((oct0 ^ sw)*8 + wi)) =
        make_uint2(pk_rne(o0[0]*inv, o0[1]*inv), pk_rne(o0[2]*inv, o0[3]*inv));
    *(uint2*)(oS + tokLoc*64 + (((oct0+2) ^ sw)*8 + wi)) =
        make_uint2(pk_rne(o1[0]*inv, o1[1]*inv), pk_rne(o1[2]*inv, o1[3]*inv));
    __syncthreads();                          // B(it): oS visible; keyS/vTS reads done

    // issue next stage + next q NOW — in flight under proj(it) and barrier A
    if (it < 5){
      stage(2*(it + 1));
      aq = *(const bf16x8*)(qhm + (bbase + 2*(it+1) + hsel)*8192*32 + qoff);
    }

    // proj accumulate: BK=64 (this head-pair's channels); B direct from L2
    #pragma unroll
    for (int kk = 0; kk < 2; kk++){
      bf16x8 af[4];
      #pragma unroll
      for (int i = 0; i < 4; i++)
        af[i] = *(const bf16x8*)(oS + (i*16 + l15)*64 + (((kk<<2)+quad) ^ sw)*8);
      #pragma unroll
      for (int j = 0; j < 3; j++){
        bf16x8 bfr = *(const bf16x8*)(projwb + (long)(wave*48 + j*16 + l15)*384
                                      + it*64 + (kk*4 + quad)*8);
        #pragma unroll
        for (int i = 0; i < 4; i++)
          acc[i][j] = MFMA16(af[i], bfr, acc[i][j]);
      }
    }
    if (it < 5) __syncthreads();              // A(it+1): drains stage(it+1)
  }

  // epilogue: f32 token-major
  #pragma unroll
  for (int j = 0; j < 3; j++){
    int col = wave*48 + j*16 + l15;
    float bv = proj_b[col];
    #pragma unroll
    for (int i = 0; i < 4; i++){
      long row0 = (long)b*8192 + t0 + i*16 + quad*4;
      #pragma unroll
      for (int r = 0; r < 4; r++)
        out[(row0 + r)*384 + col] = acc[i][j][r] + bv;
    }
  }
}

extern "C" void kernel_launch(void* const* d_in, const int* in_sizes, int n_in,
                              void* d_out, int out_size, void* d_ws, size_t ws_size,
                              hipStream_t stream)
{
  const float* pos      = (const float*)d_in[0];
  const float* feat     = (const float*)d_in[1];
  const int* member_idx = (const int*)d_in[2];
  const int* batch_idx  = (const int*)d_in[3];
  const float* qkv_w    = (const float*)d_in[4];
  const float* qkv_b    = (const float*)d_in[5];
  const float* pos_w    = (const float*)d_in[6];
  const float* pos_b    = (const float*)d_in[7];
  const float* proj_w   = (const float*)d_in[8];
  const float* proj_b   = (const float*)d_in[9];
  float* out = (float*)d_out;

  char* ws = (char*)d_ws;
  float* pmax           = (float*)ws;                       // 8 B
  float* pm             = (float*)(ws + 256);               // 8 KB
  unsigned short* fm    = (unsigned short*)(ws + 8704);     // 1024x384 bf16
  unsigned short* kh    = (unsigned short*)(ws + 795136);   // 4x12x256x32 bf16
  unsigned short* vt    = (unsigned short*)(ws + 1581568);  // 4x12x32x256 bf16
  unsigned short* wt    = (unsigned short*)(ws + 2368000);  // 4x12x256 bf16
  unsigned short* q_s   = (unsigned short*)(ws + 2417152);  // 48x8192x32 bf16 (head-major)
  unsigned short* qkvwb = (unsigned short*)(ws + 52748800); // 1152x384 bf16
  unsigned short* projwb= (unsigned short*)(ws + 53633536); // 384x384 bf16
  unsigned short* featb = (unsigned short*)(ws + 53928448); // 32768x384 bf16 (25.2 MB)

  hipMemsetAsync(pmax, 0, 8, stream);
  prep_means_kernel<<<1494, 192, 0, stream>>>(pos, (unsigned*)pmax, qkv_w, qkvwb,
                                              proj_w, projwb, feat, member_idx,
                                              batch_idx, fm, pm, featb);
  // kv GEMM (96 blocks, incl. wt fold) + 512 q-tiles in one 512-block launch
  kvq_kernel<<<512, 512, 0, stream>>>(fm, featb, qkvwb, qkv_b, pm, pmax, pos_w, pos_b,
                                      kh, vt, wt, q_s,
                                      0.17677669529663687f * 1.44269504088896340f);
  // fused attention + output projection (async stage issue under proj)
  attnproj_kernel<<<512, 512, 0, stream>>>(q_s, kh, vt, wt, projwb, proj_b, out);
}